// Round 1
// baseline (141.870 us; speedup 1.0000x reference)
//
#include <hip/hip_runtime.h>
#include <hip/hip_bf16.h>
#include <cstdint>

#define BATCH 16
#define NN    1024
#define FF    64
#define OUTF  128
#define KCAT  192
#define EPSV  1e-6f

typedef __attribute__((ext_vector_type(4))) float  f32x4;
typedef __attribute__((ext_vector_type(8))) __bf16 bf16x8;
typedef __attribute__((ext_vector_type(4))) __bf16 bf16x4;

// ---------------------------------------------------------------------------
// Kernel 1: degree per row.  deg[b,i] = 1 + sum_j A[b,i,j] - A[b,i,i]
// One wave per row; float4 loads; shuffle reduce.
// ---------------------------------------------------------------------------
__global__ __launch_bounds__(256) void k_deg(const float* __restrict__ A,
                                             float* __restrict__ d1,
                                             float* __restrict__ sArr) {
    int wave = threadIdx.x >> 6;
    int lane = threadIdx.x & 63;
    int row  = blockIdx.x * 4 + wave;          // [0, 16384)
    const f32x4* rp = (const f32x4*)(A + (size_t)row * NN);
    float sum = 0.f;
#pragma unroll
    for (int t = 0; t < 4; ++t) {
        f32x4 v = rp[t * 64 + lane];
        sum += v[0] + v[1] + v[2] + v[3];
    }
#pragma unroll
    for (int off = 32; off; off >>= 1) sum += __shfl_xor(sum, off);
    if (lane == 0) {
        int i = row & (NN - 1);
        float diag = A[(size_t)row * NN + i];
        float deg  = 1.0f + sum - diag;
        d1[row]   = 1.0f / (EPSV + deg);
        sArr[row] = 1.0f / (EPSV + sqrtf(deg));
    }
}

// ---------------------------------------------------------------------------
// Kernel 2: build K-major bf16 copies of x and s*x, plus transposed bf16 K.
//   xT[b][f][n]  = bf16(x[b][n][f])
//   sxT[b][f][n] = bf16(s[b][n] * x[b][n][f])
//   KT[c][k]     = bf16(kernel[k][c])        (c<128, k<192)
// ---------------------------------------------------------------------------
__global__ __launch_bounds__(256) void k_prep(const float* __restrict__ x,
                                              const float* __restrict__ sArr,
                                              const float* __restrict__ kern,
                                              __bf16* __restrict__ xT,
                                              __bf16* __restrict__ sxT,
                                              __bf16* __restrict__ KT) {
    __shared__ float tile[64][65];
    int bid = blockIdx.x;                  // 0..255
    int b   = bid >> 4;
    int k0  = (bid & 15) * 64;
    const float* xp = x + ((size_t)b * NN + k0) * FF;
    for (int i = threadIdx.x; i < 64 * 64; i += 256) {
        int r = i >> 6, c = i & 63;
        tile[r][c] = xp[r * FF + c];
    }
    __syncthreads();
    for (int i = threadIdx.x; i < 64 * 64; i += 256) {
        int c = i >> 6, kk = i & 63;
        float v  = tile[kk][c];
        float sv = v * sArr[b * NN + k0 + kk];
        size_t o = ((size_t)b * FF + c) * NN + k0 + kk;
        xT[o]  = (__bf16)v;
        sxT[o] = (__bf16)sv;
    }
    // KT: 24576 elems spread over 256 blocks (96 each)
    if (threadIdx.x < 96) {
        int idx = bid * 96 + threadIdx.x;
        int c = idx / KCAT;
        int k = idx - c * KCAT;
        KT[idx] = (__bf16)kern[k * OUTF + c];
    }
}

// ---------------------------------------------------------------------------
// Kernel 3: main fused kernel.
// Grid 256 = 16 batches x 16 row-tiles (BM=64). 512 threads = 8 waves.
// K-loop: stage A f32 tile (diag zeroed) + xT/sxT bf16 tiles; MFMA P and Q.
// Epilogue: o1/o2/o3 -> bf16 LDS -> MFMA vs KT -> bias+relu -> f32 out.
// Wave w: row-group rg = w>>1 (rows rg*16..+15), col-half ch = w&1.
// ---------------------------------------------------------------------------
__global__ __launch_bounds__(512) void k_main(const float* __restrict__ A,
                                              const float* __restrict__ x,
                                              const float* __restrict__ bias,
                                              const float* __restrict__ d1g,
                                              const float* __restrict__ sg,
                                              const __bf16* __restrict__ xT,
                                              const __bf16* __restrict__ sxT,
                                              const __bf16* __restrict__ KT,
                                              float* __restrict__ out) {
    __shared__ __align__(16) float  As[64][32];   // A tile, f32, diag zeroed
    __shared__ __align__(16) __bf16 xs[64][32];   // xT tile (col-major: [feature][k])
    __shared__ __align__(16) __bf16 ss[64][32];   // sxT tile
    __shared__ __align__(16) __bf16 os[64][192];  // concat(o1,o2,o3) for epilogue

    const int tid  = threadIdx.x;
    const int wave = tid >> 6;
    const int lane = tid & 63;
    const int bid  = blockIdx.x;
    const int b    = bid >> 4;
    const int row0 = (bid & 15) * 64;

    const float*  Ab  = A   + (size_t)b * NN * NN;
    const __bf16* xTb = xT  + (size_t)b * FF * NN;
    const __bf16* sTb = sxT + (size_t)b * FF * NN;

    // staging assignments (constant per thread)
    const int ar = tid >> 3;          // A tile row 0..63
    const int ac = (tid & 7) * 4;     // A tile col (float4)
    const int xc = tid >> 3;          // x tile row (feature) 0..63
    const int xk = (tid & 7) * 4;     // x tile k (bf16x4)

    f32x4  aReg;
    bf16x4 xReg, sReg;

    auto LOAD = [&](int t) {
        int kk = t * 32;
        aReg = *(const f32x4*)(Ab + (size_t)(row0 + ar) * NN + kk + ac);
        int d = (row0 + ar) - (kk + ac);   // zero the diagonal element if in range
#pragma unroll
        for (int q = 0; q < 4; ++q)
            if (d == q) aReg[q] = 0.f;
        xReg = *(const bf16x4*)(xTb + (size_t)xc * NN + kk + xk);
        sReg = *(const bf16x4*)(sTb + (size_t)xc * NN + kk + xk);
    };
    auto WRITE = [&]() {
        *(f32x4*)&As[ar][ac]  = aReg;
        *(bf16x4*)&xs[xc][xk] = xReg;
        *(bf16x4*)&ss[xc][xk] = sReg;
    };

    const int rg = wave >> 1;          // row group
    const int ch = wave & 1;           // col half
    const int l15 = lane & 15;
    const int h8  = (lane >> 4) * 8;

    f32x4 P[2] = {};
    f32x4 Q[2] = {};

    LOAD(0);
    for (int t = 0; t < 32; ++t) {
        WRITE();
        __syncthreads();
        if (t < 31) LOAD(t + 1);

        // A fragment: rows rg*16 + (lane&15), k = h8..h8+7  (f32 -> bf16)
        const int arow = rg * 16 + l15;
        f32x4 a0 = *(const f32x4*)&As[arow][h8];
        f32x4 a1 = *(const f32x4*)&As[arow][h8 + 4];
        bf16x8 af;
#pragma unroll
        for (int i = 0; i < 4; ++i) {
            af[i]     = (__bf16)a0[i];
            af[i + 4] = (__bf16)a1[i];
        }
#pragma unroll
        for (int g = 0; g < 2; ++g) {
            int col = ch * 32 + g * 16 + l15;
            bf16x8 xf = *(const bf16x8*)&xs[col][h8];
            bf16x8 sf = *(const bf16x8*)&ss[col][h8];
            P[g] = __builtin_amdgcn_mfma_f32_16x16x32_bf16(af, xf, P[g], 0, 0, 0);
            Q[g] = __builtin_amdgcn_mfma_f32_16x16x32_bf16(af, sf, Q[g], 0, 0, 0);
        }
        __syncthreads();
    }

    // ---- epilogue: build o = [o1 | o2 | o3] in LDS as bf16 ----
    // P/Q frag (g): value row = rg*16 + (lane>>4)*4 + j, col = ch*32+g*16+(lane&15)
#pragma unroll
    for (int j = 0; j < 4; ++j) {
        int rr   = rg * 16 + (lane >> 4) * 4 + j;       // local row
        int grow = b * NN + row0 + rr;
        float dv = d1g[grow];
        float sv = sg[grow];
#pragma unroll
        for (int g = 0; g < 2; ++g) {
            int cc = ch * 32 + g * 16 + l15;
            float xv = x[((size_t)b * NN + row0 + rr) * FF + cc];
            float o1 = P[g][j];
            float o2 = dv * (P[g][j] + xv);
            float o3 = sv * (Q[g][j] + sv * xv);
            os[rr][cc]       = (__bf16)o1;
            os[rr][64 + cc]  = (__bf16)o2;
            os[rr][128 + cc] = (__bf16)o3;
        }
    }
    __syncthreads();

    // ---- epilogue GEMM: out[64x128] = relu(os[64x192] @ K[192x128] + bias)
    // wave w: rows rg*16..+15, cols ch*64 + cg*16, cg=0..3
    f32x4 acc[4] = {};
    const int orow = rg * 16 + l15;
#pragma unroll
    for (int ks = 0; ks < 6; ++ks) {
        bf16x8 of = *(const bf16x8*)&os[orow][ks * 32 + h8];
#pragma unroll
        for (int cg = 0; cg < 4; ++cg) {
            int col = ch * 64 + cg * 16 + l15;
            bf16x8 kf = *(const bf16x8*)&KT[(size_t)col * KCAT + ks * 32 + h8];
            acc[cg] = __builtin_amdgcn_mfma_f32_16x16x32_bf16(of, kf, acc[cg], 0, 0, 0);
        }
    }
#pragma unroll
    for (int cg = 0; cg < 4; ++cg) {
        int col  = ch * 64 + cg * 16 + l15;
        float bv = bias[col];
#pragma unroll
        for (int j = 0; j < 4; ++j) {
            int rr  = rg * 16 + (lane >> 4) * 4 + j;
            float v = acc[cg][j] + bv;
            out[((size_t)b * NN + row0 + rr) * OUTF + col] = v > 0.f ? v : 0.f;
        }
    }
}

// ---------------------------------------------------------------------------
extern "C" void kernel_launch(void* const* d_in, const int* in_sizes, int n_in,
                              void* d_out, int out_size, void* d_ws, size_t ws_size,
                              hipStream_t stream) {
    const float* x    = (const float*)d_in[0];
    const float* A    = (const float*)d_in[1];
    const float* kern = (const float*)d_in[2];
    const float* bias = (const float*)d_in[3];
    float* out = (float*)d_out;

    char* ws = (char*)d_ws;
    float*  d1  = (float*)(ws);                               // 16384 f32
    float*  s   = (float*)(ws + 65536);                       // 16384 f32
    __bf16* xT  = (__bf16*)(ws + 131072);                     // 16*64*1024 bf16 (2MB)
    __bf16* sxT = (__bf16*)(ws + 131072 + 2097152);           // 2MB
    __bf16* KT  = (__bf16*)(ws + 131072 + 2 * 2097152);       // 128*192 bf16
    (void)ws_size; (void)in_sizes; (void)n_in; (void)out_size;

    k_deg<<<dim3(4096), dim3(256), 0, stream>>>(A, d1, s);
    k_prep<<<dim3(256), dim3(256), 0, stream>>>(x, s, kern, xT, sxT, KT);
    k_main<<<dim3(256), dim3(512), 0, stream>>>(A, x, bias, d1, s, xT, sxT, KT, out);
}